// Round 1
// 258.753 us; speedup vs baseline: 1.0201x; 1.0201x over previous
//
#include <hip/hip_runtime.h>
#include <stdint.h>

#define M_DIM 4096
#define T_DIM 2048
#define N_OUT 2024
#define N_PAD 2048
#define WIN   25
#define K_DIM 4096

typedef float f32x4 __attribute__((ext_vector_type(4)));

__device__ __forceinline__ unsigned short f2bf(float x) {
  unsigned u = __float_as_uint(x);
  u += 0x7FFF + ((u >> 16) & 1);           // round-to-nearest-even
  return (unsigned short)(u >> 16);
}
__device__ __forceinline__ float bf2f(unsigned short h) {
  return __uint_as_float(((unsigned)h) << 16);
}

__device__ __forceinline__ void gl2lds16(const void* g, void* l) {
  // 16B-wide async global->LDS; HW dest = wave-uniform base + lane*16
  __builtin_amdgcn_global_load_lds(
      (const __attribute__((address_space(1))) unsigned int*)g,
      (__attribute__((address_space(3))) unsigned int*)l, 16, 0, 0);
}

// pack 4 floats -> 4 e4m3 bytes (one dword)
__device__ __forceinline__ int pk_fp8x4(float a, float b, float c, float d) {
  int w = __builtin_amdgcn_cvt_pk_fp8_f32(a, b, 0, false);
  w = __builtin_amdgcn_cvt_pk_fp8_f32(c, d, w, true);
  return w;
}

// ---------- Kernel 1: W8 = e4m3(sigmoid(alphas)), diagonal -> 0 ----------
__global__ __launch_bounds__(256) void k_wcast(const float* __restrict__ alphas,
                                               unsigned char* __restrict__ W8) {
  size_t i8 = ((size_t)blockIdx.x * 256 + threadIdx.x) * 8;
  const float4 v0 = *(const float4*)(alphas + i8);
  const float4 v1 = *(const float4*)(alphas + i8 + 4);
  int row = (int)(i8 >> 12);
  int col = (int)(i8 & 4095);
  float a[8] = {v0.x, v0.y, v0.z, v0.w, v1.x, v1.y, v1.z, v1.w};
  float w[8];
#pragma unroll
  for (int j = 0; j < 8; ++j)
    w[j] = (row == col + j) ? 0.f : 1.f / (1.f + __expf(-a[j]));
  int p0 = pk_fp8x4(w[0], w[1], w[2], w[3]);
  int p1 = pk_fp8x4(w[4], w[5], w[6], w[7]);
  *(uint2*)(W8 + i8) = uint2{(unsigned)p0, (unsigned)p1};
}

// ---------- Kernel 2: S = bf16(softplus(depthwise_conv(ys, repro))) ----------
__global__ __launch_bounds__(256) void k_conv(const float* __restrict__ ys,
                                              const float* __restrict__ repro,
                                              unsigned short* __restrict__ Sbf) {
  __shared__ float sy[256 + WIN - 1];
  __shared__ float sr[WIN];
  int m = blockIdx.y;
  int j0 = blockIdx.x * 256;
  int tid = threadIdx.x;
  sy[tid] = ys[(size_t)m * T_DIM + j0 + tid];
  if (tid < WIN - 1) {
    int jj = j0 + 256 + tid;
    sy[256 + tid] = (jj < T_DIM) ? ys[(size_t)m * T_DIM + jj] : 0.f;
  }
  if (tid < WIN) sr[tid] = repro[m * WIN + tid];
  __syncthreads();
  int j = j0 + tid;
  float z = 0.f;
#pragma unroll
  for (int k = 0; k < WIN; ++k) z += sy[tid + k] * sr[k];
  float sp = fmaxf(z, 0.f) + log1pf(__expf(-fabsf(z)));
  Sbf[(size_t)m * N_PAD + j] = (j < N_OUT) ? f2bf(sp) : (unsigned short)0;
}

// ---------- Kernel 3: BT8[n][k] = e4m3(ys[k][n+24]), zero-pad n>=2024 ----------
__global__ __launch_bounds__(256) void k_transpose(const float* __restrict__ ys,
                                                   unsigned char* __restrict__ BT8) {
  __shared__ float t[64][65];
  int n0 = blockIdx.x * 64;
  int k0 = blockIdx.y * 64;
  int tx = threadIdx.x;  // 0..63
  int ty = threadIdx.y;  // 0..3
#pragma unroll
  for (int r = 0; r < 16; ++r) {
    int kk = k0 + ty + r * 4;
    int n = n0 + tx;
    t[ty + r * 4][tx] = (n < N_OUT) ? ys[(size_t)kk * T_DIM + n + (WIN - 1)] : 0.f;
  }
  __syncthreads();
  int tid = ty * 64 + tx;
  int nl = tid >> 2;          // 0..63
  int kc = (tid & 3) * 16;    // 0,16,32,48
  unsigned wds[4];
#pragma unroll
  for (int w = 0; w < 4; ++w)
    wds[w] = (unsigned)pk_fp8x4(t[kc + 4 * w][nl], t[kc + 4 * w + 1][nl],
                                t[kc + 4 * w + 2][nl], t[kc + 4 * w + 3][nl]);
  *(uint4*)(BT8 + (size_t)(n0 + nl) * K_DIM + k0 + kc) =
      uint4{wds[0], wds[1], wds[2], wds[3]};
}

// ---------- Kernel 4: C = W8 @ BT8^T (fp8 MFMA), out = beta * (S + C) ----------
// R8: depth-2 software pipeline (T3+T4). R7's counters (MfmaUtil 15.7%,
// VALUBusy 25%, HBM 9.6%, all idle; 6400 cy/kstep vs ~700 cy of work) showed
// the binding constraint is NOT ingest BW but the single-buffered
// stage->__syncthreads() vmcnt(0) drain: full load latency exposed every
// k-step with only 2 blocks/CU of TLP to hide it. Fix: 4 LDS buffers,
// counted s_waitcnt vmcnt(8) (loads for tile t+2 stay in flight across two
// compute phases), raw s_barrier (never __syncthreads -> no forced drain).
// Fragment layout / XOR chunk swizzle / epilogue identical to R7; same
// accumulation order -> bitwise-identical output.
__global__ __launch_bounds__(256) void k_gemm(const unsigned char* __restrict__ W8,
                                              const unsigned char* __restrict__ BT8,
                                              const unsigned short* __restrict__ Sbf,
                                              const float* __restrict__ b0,
                                              const float* __restrict__ b1,
                                              float* __restrict__ out) {
  __shared__ __align__(64) unsigned char lA[4][128 * 64];   // 32 KB
  __shared__ __align__(64) unsigned char lB[4][128 * 64];   // 32 KB
  const int tid  = threadIdx.x;
  const int wave = tid >> 6;          // 0..3
  const int lane = tid & 63;
  const int wm = wave >> 1, wn = wave & 1;
  const int m16  = lane & 15;
  const int quad = lane >> 4;
  const int tileM = blockIdx.y * 128;
  const int tileN = blockIdx.x * 128;

  // fragment read offsets: row = w*64 + i*16 + m16, 64B rows (K=64 fp8).
  // MFMA h (k-half, K=32 each): lane needs bytes k = h*32 + quad*8 .. +7
  // chunk c = 2h + (quad>>1), swizzled slot = c ^ ((m16>>1)&3), sub = (quad&1)*8
  const int key  = (m16 >> 1) & 3;
  const int sub  = (quad & 1) * 8;
  const int rowA = (wm * 64 + m16) * 64;
  const int rowB = (wn * 64 + m16) * 64;
  int hOf[2];
#pragma unroll
  for (int h = 0; h < 2; ++h)
    hOf[h] = (((2 * h + (quad >> 1)) ^ key) << 4) + sub;

  // staging: 2 chunks/thread/matrix (8KB per matrix per kstep);
  // global addr carries the XOR swizzle, LDS dest stays linear
  const unsigned char* gA[2];
  const unsigned char* gB[2];
  int ldsOff[2];
#pragma unroll
  for (int c = 0; c < 2; ++c) {
    int o  = c * 4096 + wave * 1024 + lane * 16;   // 0..8191
    int r  = o >> 6;                    // LDS row 0..127 (64B rows)
    int s  = (o >> 4) & 3;              // LDS chunk slot
    int q  = s ^ ((r >> 1) & 3);        // logical (global) chunk
    gA[c] = W8  + (size_t)(tileM + r) * K_DIM + q * 16;
    gB[c] = BT8 + (size_t)(tileN + r) * K_DIM + q * 16;
    ldsOff[c] = c * 4096 + wave * 1024;   // wave-uniform base
  }

  f32x4 acc[4][4];
#pragma unroll
  for (int i = 0; i < 4; ++i)
#pragma unroll
    for (int j = 0; j < 4; ++j) acc[i][j] = f32x4{0.f, 0.f, 0.f, 0.f};

  // tile t lives in buffer t & 3; 4 gl2lds (vmcnt events) per tile per wave
  auto stage = [&](int buf, int kt_) {
    const size_t kb_ = (size_t)kt_ * 64;
#pragma unroll
    for (int c = 0; c < 2; ++c) {
      gl2lds16(gA[c] + kb_, &lA[buf][ldsOff[c]]);
      gl2lds16(gB[c] + kb_, &lB[buf][ldsOff[c]]);
    }
  };
  auto compute = [&](int buf) {
#pragma unroll
    for (int h = 0; h < 2; ++h) {
      long long aF[4], bF[4];
#pragma unroll
      for (int i = 0; i < 4; ++i) {
        aF[i] = *(const long long*)&lA[buf][rowA + i * 1024 + hOf[h]];
        bF[i] = *(const long long*)&lB[buf][rowB + i * 1024 + hOf[h]];
      }
#pragma unroll
      for (int i = 0; i < 4; ++i)
#pragma unroll
        for (int j = 0; j < 4; ++j)
          acc[i][j] = __builtin_amdgcn_mfma_f32_16x16x32_fp8_fp8(
              aF[i], bF[j], acc[i][j], 0, 0, 0);
    }
  };

  // prologue: tiles 0 and 1 in flight (8 outstanding per wave)
  stage(0, 0);
  stage(1, 1);

#pragma unroll 1
  for (int kt = 0; kt < K_DIM / 64; kt += 4) {
    // phase 0: prefetch kt+2, compute kt (buf0)
    stage(2, kt + 2);                                  // 12 outstanding
    asm volatile("s_waitcnt vmcnt(8)" ::: "memory");   // tile kt landed
    __builtin_amdgcn_s_barrier();
    asm volatile("" ::: "memory");
    compute(0);
    __builtin_amdgcn_s_barrier();                      // buf0 free for reuse
    asm volatile("" ::: "memory");

    // phase 1: prefetch kt+3, compute kt+1 (buf1)
    stage(3, kt + 3);
    asm volatile("s_waitcnt vmcnt(8)" ::: "memory");
    __builtin_amdgcn_s_barrier();
    asm volatile("" ::: "memory");
    compute(1);
    __builtin_amdgcn_s_barrier();
    asm volatile("" ::: "memory");

    // phase 2: prefetch kt+4, compute kt+2 (buf2)
    if (kt + 4 < K_DIM / 64) {
      stage(0, kt + 4);
      asm volatile("s_waitcnt vmcnt(8)" ::: "memory");
    } else {
      asm volatile("s_waitcnt vmcnt(4)" ::: "memory"); // tail: tile kt+2 landed
    }
    __builtin_amdgcn_s_barrier();
    asm volatile("" ::: "memory");
    compute(2);
    __builtin_amdgcn_s_barrier();
    asm volatile("" ::: "memory");

    // phase 3: prefetch kt+5, compute kt+3 (buf3)
    if (kt + 5 < K_DIM / 64) {
      stage(1, kt + 5);
      asm volatile("s_waitcnt vmcnt(8)" ::: "memory");
    } else {
      asm volatile("s_waitcnt vmcnt(0)" ::: "memory"); // tail: all landed
    }
    __builtin_amdgcn_s_barrier();
    asm volatile("" ::: "memory");
    compute(3);
    __builtin_amdgcn_s_barrier();
    asm volatile("" ::: "memory");
  }

  // Epilogue: out[gm][gn] = softplus(b0+b1*(gn+25)) * (S[gm][gn] + C)
#pragma unroll
  for (int j = 0; j < 4; ++j) {
    int gn = tileN + wn * 64 + j * 16 + m16;
    if (gn >= N_OUT) continue;
    float tval = (float)(gn + WIN);
#pragma unroll
    for (int i = 0; i < 4; ++i) {
#pragma unroll
      for (int r = 0; r < 4; ++r) {
        int gm = tileM + wm * 64 + i * 16 + quad * 4 + r;
        float x = b0[gm] + b1[gm] * tval;
        float beta = fmaxf(x, 0.f) + log1pf(__expf(-fabsf(x)));
        float s = bf2f(Sbf[(size_t)gm * N_PAD + gn]);
        out[(size_t)gm * N_OUT + gn] = beta * (s + acc[i][j][r]);
      }
    }
  }
}

extern "C" void kernel_launch(void* const* d_in, const int* in_sizes, int n_in,
                              void* d_out, int out_size, void* d_ws, size_t ws_size,
                              hipStream_t stream) {
  const float* ys     = (const float*)d_in[0];
  const float* alphas = (const float*)d_in[1];
  const float* repro  = (const float*)d_in[2];
  const float* b0     = (const float*)d_in[3];
  const float* b1     = (const float*)d_in[4];
  float* out = (float*)d_out;

  char* ws = (char*)d_ws;
  unsigned char*  W8  = (unsigned char*)ws;                                    // 16 MiB
  unsigned char*  BT8 = (unsigned char*)(ws + (size_t)M_DIM * K_DIM);          //  8 MiB
  unsigned short* Sbf = (unsigned short*)(ws + (size_t)M_DIM * K_DIM
                                             + (size_t)N_PAD * K_DIM);         // 16 MiB

  k_wcast<<<(M_DIM * (size_t)K_DIM) / 8 / 256, 256, 0, stream>>>(alphas, W8);
  k_conv<<<dim3(T_DIM / 256, M_DIM), 256, 0, stream>>>(ys, repro, Sbf);
  k_transpose<<<dim3(N_PAD / 64, K_DIM / 64), dim3(64, 4), 0, stream>>>(ys, BT8);
  k_gemm<<<dim3(N_PAD / 128, M_DIM / 128), 256, 0, stream>>>(W8, BT8, Sbf, b0, b1, out);
}

// Round 2
// 252.684 us; speedup vs baseline: 1.0446x; 1.0240x over previous
//
#include <hip/hip_runtime.h>
#include <stdint.h>

#define M_DIM 4096
#define T_DIM 2048
#define N_OUT 2024
#define N_PAD 2048
#define WIN   25
#define K_DIM 4096

typedef float f32x4 __attribute__((ext_vector_type(4)));

__device__ __forceinline__ unsigned short f2bf(float x) {
  unsigned u = __float_as_uint(x);
  u += 0x7FFF + ((u >> 16) & 1);           // round-to-nearest-even
  return (unsigned short)(u >> 16);
}
__device__ __forceinline__ float bf2f(unsigned short h) {
  return __uint_as_float(((unsigned)h) << 16);
}

__device__ __forceinline__ void gl2lds16(const void* g, void* l) {
  // 16B-wide async global->LDS; HW dest = wave-uniform base + lane*16
  __builtin_amdgcn_global_load_lds(
      (const __attribute__((address_space(1))) unsigned int*)g,
      (__attribute__((address_space(3))) unsigned int*)l, 16, 0, 0);
}

// pack 4 floats -> 4 e4m3 bytes (one dword)
__device__ __forceinline__ int pk_fp8x4(float a, float b, float c, float d) {
  int w = __builtin_amdgcn_cvt_pk_fp8_f32(a, b, 0, false);
  w = __builtin_amdgcn_cvt_pk_fp8_f32(c, d, w, true);
  return w;
}

// ---------- Kernel 1: W8 = e4m3(sigmoid(alphas)), diagonal -> 0 ----------
__global__ __launch_bounds__(256) void k_wcast(const float* __restrict__ alphas,
                                               unsigned char* __restrict__ W8) {
  size_t i8 = ((size_t)blockIdx.x * 256 + threadIdx.x) * 8;
  const float4 v0 = *(const float4*)(alphas + i8);
  const float4 v1 = *(const float4*)(alphas + i8 + 4);
  int row = (int)(i8 >> 12);
  int col = (int)(i8 & 4095);
  float a[8] = {v0.x, v0.y, v0.z, v0.w, v1.x, v1.y, v1.z, v1.w};
  float w[8];
#pragma unroll
  for (int j = 0; j < 8; ++j)
    w[j] = (row == col + j) ? 0.f : 1.f / (1.f + __expf(-a[j]));
  int p0 = pk_fp8x4(w[0], w[1], w[2], w[3]);
  int p1 = pk_fp8x4(w[4], w[5], w[6], w[7]);
  *(uint2*)(W8 + i8) = uint2{(unsigned)p0, (unsigned)p1};
}

// ---------- Kernel 2: S = bf16(softplus(depthwise_conv(ys, repro))) ----------
__global__ __launch_bounds__(256) void k_conv(const float* __restrict__ ys,
                                              const float* __restrict__ repro,
                                              unsigned short* __restrict__ Sbf) {
  __shared__ float sy[256 + WIN - 1];
  __shared__ float sr[WIN];
  int m = blockIdx.y;
  int j0 = blockIdx.x * 256;
  int tid = threadIdx.x;
  sy[tid] = ys[(size_t)m * T_DIM + j0 + tid];
  if (tid < WIN - 1) {
    int jj = j0 + 256 + tid;
    sy[256 + tid] = (jj < T_DIM) ? ys[(size_t)m * T_DIM + jj] : 0.f;
  }
  if (tid < WIN) sr[tid] = repro[m * WIN + tid];
  __syncthreads();
  int j = j0 + tid;
  float z = 0.f;
#pragma unroll
  for (int k = 0; k < WIN; ++k) z += sy[tid + k] * sr[k];
  float sp = fmaxf(z, 0.f) + log1pf(__expf(-fabsf(z)));
  Sbf[(size_t)m * N_PAD + j] = (j < N_OUT) ? f2bf(sp) : (unsigned short)0;
}

// ---------- Kernel 3: BT8[n][k] = e4m3(ys[k][n+24]), zero-pad n>=2024 ----------
__global__ __launch_bounds__(256) void k_transpose(const float* __restrict__ ys,
                                                   unsigned char* __restrict__ BT8) {
  __shared__ float t[64][65];
  int n0 = blockIdx.x * 64;
  int k0 = blockIdx.y * 64;
  int tx = threadIdx.x;  // 0..63
  int ty = threadIdx.y;  // 0..3
#pragma unroll
  for (int r = 0; r < 16; ++r) {
    int kk = k0 + ty + r * 4;
    int n = n0 + tx;
    t[ty + r * 4][tx] = (n < N_OUT) ? ys[(size_t)kk * T_DIM + n + (WIN - 1)] : 0.f;
  }
  __syncthreads();
  int tid = ty * 64 + tx;
  int nl = tid >> 2;          // 0..63
  int kc = (tid & 3) * 16;    // 0,16,32,48
  unsigned wds[4];
#pragma unroll
  for (int w = 0; w < 4; ++w)
    wds[w] = (unsigned)pk_fp8x4(t[kc + 4 * w][nl], t[kc + 4 * w + 1][nl],
                                t[kc + 4 * w + 2][nl], t[kc + 4 * w + 3][nl]);
  *(uint4*)(BT8 + (size_t)(n0 + nl) * K_DIM + k0 + kc) =
      uint4{wds[0], wds[1], wds[2], wds[3]};
}

// ---------- Kernel 4: C = W8 @ BT8^T (fp8 MFMA), out = beta * (S + C) ----------
// R9: parallelism, not pipeline-depth. R8's depth-2 pipeline moved nothing:
// per-kstep wall stayed ~5960 cy — same structural constant m97 shows. The
// regime is latency-bound at the WAVE level; throughput = resident waves /
// kstep latency. R8 had only 8 waves/CU (grid 512 = 2 blocks/CU, 4 waves).
// Fix: 512-thread blocks (8 waves, wave = 64x32 out, acc 32 VGPR) -> 16
// waves/CU at the same tile/memory pattern. Keep counted-vmcnt pipeline,
// deepen to 3 tiles in flight. Add bijective XCD swizzle (512%8==0): each
// XCD owns 4 contiguous M-rows of tiles -> A-panels L2-resident.
// Accumulation order per output element unchanged -> identical numerics.
__global__ __launch_bounds__(512, 4) void k_gemm(const unsigned char* __restrict__ W8,
                                                 const unsigned char* __restrict__ BT8,
                                                 const unsigned short* __restrict__ Sbf,
                                                 const float* __restrict__ b0,
                                                 const float* __restrict__ b1,
                                                 float* __restrict__ out) {
  __shared__ __align__(64) unsigned char lA[4][128 * 64];   // 32 KB
  __shared__ __align__(64) unsigned char lB[4][128 * 64];   // 32 KB
  const int tid  = threadIdx.x;
  const int wave = tid >> 6;          // 0..7
  const int lane = tid & 63;
  const int wm = wave >> 2;           // 0..1 : 64-row slice
  const int wn = wave & 3;            // 0..3 : 32-col slice
  const int m16  = lane & 15;
  const int quad = lane >> 4;

  // XCD-aware bijective swizzle: fid round-robins XCDs in HW dispatch;
  // remap so each XCD gets 64 consecutive tiles = 4 full M-rows.
  const int fid  = blockIdx.y * gridDim.x + blockIdx.x;   // 0..511
  const int swz  = (fid & 7) * 64 + (fid >> 3);
  const int tileN = (swz & 15) * 128;
  const int tileM = (swz >> 4) * 128;

  // fragment read offsets: 64B rows (K=64 fp8).
  // MFMA h (k-half, K=32): lane reads bytes k = h*32 + quad*8 .. +7
  // chunk c = 2h + (quad>>1); swizzled slot = c ^ ((row>>1)&3) = c ^ ((m16>>1)&3)
  const int key  = (m16 >> 1) & 3;
  const int sub  = (quad & 1) * 8;
  const int rowA = (wm * 64 + m16) * 64;
  const int rowB = (wn * 32 + m16) * 64;
  int hOf[2];
#pragma unroll
  for (int h = 0; h < 2; ++h)
    hOf[h] = (((2 * h + (quad >> 1)) ^ key) << 4) + sub;

  // staging: 1 chunk/thread/matrix (8 KB per matrix per kstep, 512 threads);
  // global addr carries the XOR swizzle, LDS dest stays linear
  const int o = wave * 1024 + lane * 16;   // 0..8191
  const int r = o >> 6;                    // LDS row 0..127
  const int s = (o >> 4) & 3;              // LDS chunk slot
  const int q = s ^ ((r >> 1) & 3);        // logical (global) chunk
  const unsigned char* gA = W8  + (size_t)(tileM + r) * K_DIM + q * 16;
  const unsigned char* gB = BT8 + (size_t)(tileN + r) * K_DIM + q * 16;
  const int ldsOff = wave * 1024;          // wave-uniform base

  f32x4 acc[4][2];
#pragma unroll
  for (int i = 0; i < 4; ++i)
#pragma unroll
    for (int j = 0; j < 2; ++j) acc[i][j] = f32x4{0.f, 0.f, 0.f, 0.f};

  // tile t lives in buffer t & 3; 2 gl2lds (vmcnt events) per tile per wave
  auto stage = [&](int buf, int kt_) {
    const size_t kb_ = (size_t)kt_ * 64;
    gl2lds16(gA + kb_, &lA[buf][ldsOff]);
    gl2lds16(gB + kb_, &lB[buf][ldsOff]);
  };
  auto compute = [&](int buf) {
#pragma unroll
    for (int h = 0; h < 2; ++h) {
      long long aF[4], bF[2];
#pragma unroll
      for (int i = 0; i < 4; ++i)
        aF[i] = *(const long long*)&lA[buf][rowA + i * 1024 + hOf[h]];
#pragma unroll
      for (int j = 0; j < 2; ++j)
        bF[j] = *(const long long*)&lB[buf][rowB + j * 1024 + hOf[h]];
#pragma unroll
      for (int i = 0; i < 4; ++i)
#pragma unroll
        for (int j = 0; j < 2; ++j)
          acc[i][j] = __builtin_amdgcn_mfma_f32_16x16x32_fp8_fp8(
              aF[i], bF[j], acc[i][j], 0, 0, 0);
    }
  };

  // prologue: tiles 0,1,2 in flight (6 outstanding per wave)
  stage(0, 0);
  stage(1, 1);
  stage(2, 2);

#pragma unroll 1
  for (int kt = 0; kt < K_DIM / 64; kt += 4) {
    // phase 0: prefetch kt+3, compute kt (buf0)
    stage(3, kt + 3);                                  // 8 outstanding
    asm volatile("s_waitcnt vmcnt(6)" ::: "memory");   // tile kt landed
    __builtin_amdgcn_s_barrier();
    asm volatile("" ::: "memory");
    compute(0);
    __builtin_amdgcn_s_barrier();                      // buf0 free for reuse
    asm volatile("" ::: "memory");

    // phase 1: prefetch kt+4, compute kt+1 (buf1)
    if (kt + 4 < K_DIM / 64) {
      stage(0, kt + 4);
      asm volatile("s_waitcnt vmcnt(6)" ::: "memory");
    } else {
      asm volatile("s_waitcnt vmcnt(4)" ::: "memory"); // tiles kt+2,kt+3 in flight
    }
    __builtin_amdgcn_s_barrier();
    asm volatile("" ::: "memory");
    compute(1);
    __builtin_amdgcn_s_barrier();
    asm volatile("" ::: "memory");

    // phase 2: prefetch kt+5, compute kt+2 (buf2)
    if (kt + 5 < K_DIM / 64) {
      stage(1, kt + 5);
      asm volatile("s_waitcnt vmcnt(6)" ::: "memory");
    } else {
      asm volatile("s_waitcnt vmcnt(2)" ::: "memory"); // tile kt+3 in flight
    }
    __builtin_amdgcn_s_barrier();
    asm volatile("" ::: "memory");
    compute(2);
    __builtin_amdgcn_s_barrier();
    asm volatile("" ::: "memory");

    // phase 3: prefetch kt+6, compute kt+3 (buf3)
    if (kt + 6 < K_DIM / 64) {
      stage(2, kt + 6);
      asm volatile("s_waitcnt vmcnt(6)" ::: "memory");
    } else {
      asm volatile("s_waitcnt vmcnt(0)" ::: "memory"); // all landed
    }
    __builtin_amdgcn_s_barrier();
    asm volatile("" ::: "memory");
    compute(3);
    __builtin_amdgcn_s_barrier();
    asm volatile("" ::: "memory");
  }

  // Epilogue: out[gm][gn] = softplus(b0+b1*(gn+25)) * (S[gm][gn] + C)
#pragma unroll
  for (int j = 0; j < 2; ++j) {
    int gn = tileN + wn * 32 + j * 16 + m16;
    if (gn >= N_OUT) continue;
    float tval = (float)(gn + WIN);
#pragma unroll
    for (int i = 0; i < 4; ++i) {
#pragma unroll
      for (int r2 = 0; r2 < 4; ++r2) {
        int gm = tileM + wm * 64 + i * 16 + quad * 4 + r2;
        float x = b0[gm] + b1[gm] * tval;
        float beta = fmaxf(x, 0.f) + log1pf(__expf(-fabsf(x)));
        float sv = bf2f(Sbf[(size_t)gm * N_PAD + gn]);
        out[(size_t)gm * N_OUT + gn] = beta * (sv + acc[i][j][r2]);
      }
    }
  }
}

extern "C" void kernel_launch(void* const* d_in, const int* in_sizes, int n_in,
                              void* d_out, int out_size, void* d_ws, size_t ws_size,
                              hipStream_t stream) {
  const float* ys     = (const float*)d_in[0];
  const float* alphas = (const float*)d_in[1];
  const float* repro  = (const float*)d_in[2];
  const float* b0     = (const float*)d_in[3];
  const float* b1     = (const float*)d_in[4];
  float* out = (float*)d_out;

  char* ws = (char*)d_ws;
  unsigned char*  W8  = (unsigned char*)ws;                                    // 16 MiB
  unsigned char*  BT8 = (unsigned char*)(ws + (size_t)M_DIM * K_DIM);          //  8 MiB
  unsigned short* Sbf = (unsigned short*)(ws + (size_t)M_DIM * K_DIM
                                             + (size_t)N_PAD * K_DIM);         // 16 MiB

  k_wcast<<<(M_DIM * (size_t)K_DIM) / 8 / 256, 256, 0, stream>>>(alphas, W8);
  k_conv<<<dim3(T_DIM / 256, M_DIM), 256, 0, stream>>>(ys, repro, Sbf);
  k_transpose<<<dim3(N_PAD / 64, K_DIM / 64), dim3(64, 4), 0, stream>>>(ys, BT8);
  k_gemm<<<dim3(N_PAD / 128, M_DIM / 128), 512, 0, stream>>>(W8, BT8, Sbf, b0, b1, out);
}